// Round 12
// baseline (196.048 us; speedup 1.0000x reference)
//
#include <hip/hip_runtime.h>
#include <hip/hip_cooperative_groups.h>
#include <math.h>

namespace cg = cooperative_groups;

#define PAD_IDX 0
#define BIGV 10000.0f
constexpr int B_ = 1024, S_ = 128, V_ = 200, E_ = 512, H_ = 512, T_ = 24;

// ws layout (float offsets):
constexpr int OFF_H  = 262144;   // h_ws   [200][512]
constexpr int OFF_EM = 364544;   // em_tab [200][24]
constexpr int OFF_W  = 369344;   // w_tab  [200][24]
constexpr int OFF_MX = 374144;   // emax   [200]

typedef __attribute__((ext_vector_type(8)))  short    bf8frag;   // 8 bf16
typedef __attribute__((ext_vector_type(16))) float    facc16;    // MFMA C/D
typedef __attribute__((ext_vector_type(4)))  unsigned u32x4;

__device__ __forceinline__ unsigned short f2bf(float f) {
    unsigned u = __float_as_uint(f);
    u += 0x7fffu + ((u >> 16) & 1u);
    return (unsigned short)(u >> 16);
}
__device__ __forceinline__ unsigned pkbf(float lo, float hi) {
    const unsigned a = __float_as_uint(lo), b = __float_as_uint(hi);
    return ((a + 0x8000u) >> 16) | ((b + 0x8000u) & 0xffff0000u);
}

// LDS overlay: phases are separated by barriers, so share one buffer.
struct CrfS {
    float w_s[V_ * T_];        // 19200 B
    int   tok_s[S_ * 32];      // 16384 B
    float meet[64 * 12];       // 3072 B
    float logb[64];            // 256 B
    float gp[32];              // 128 B
};
struct TrS { float tile[64][65]; };
struct HS  { float xi[2 * E_]; float part[4][64][8]; };
struct EmS { float em_row[32]; };
union SMemU { TrS t; HS h; EmS e; CrfS c; };

// ---------------------------------------------------------------------------
// ONE cooperative kernel, 200 blocks x 256 threads (co-resident; 1 block/CU).
// P0 transpose (blocks 0-63) | grid.sync | P1 h (200 blocks) | grid.sync |
// P2 emis (200 blocks) | grid.sync | P3 crf (blocks 0-31: waves 0-1 = MFMA
// meet-in-middle chain [R11 math, absmax 0.0], waves 2-3 = gold, concurrent).
// R11 post-mortem: 4 structurally different crf implementations all land at
// ~30us -> the invariant is the 5-dispatch serial structure, not compute.
// Fusing deletes 4 dispatch/drain boundaries and makes the kernel visible
// in top-5 with real counters.
// ---------------------------------------------------------------------------
__global__ __launch_bounds__(256) void fused_kernel(
    const int* __restrict__ seq, const int* __restrict__ labels,
    const float* __restrict__ emb, const float* __restrict__ w1,
    const float* __restrict__ b1, const float* __restrict__ w2,
    const float* __restrict__ b2, const float* __restrict__ start_t,
    const float* __restrict__ end_t, const float* __restrict__ trans,
    unsigned short* __restrict__ w1Tb, float* __restrict__ h_ws,
    float* __restrict__ em_table, float* __restrict__ w_table,
    float* __restrict__ emax_arr, float* __restrict__ out)
{
    __shared__ __align__(16) SMemU sm;
    cg::grid_group grid = cg::this_grid();
    const int tid = threadIdx.x;
    const int blk = blockIdx.x;

    // ---- P0: transpose w1 -> bf16 (64 tiles, blocks 0..63) ----------------
    if (blk == 0 && tid == 0) out[0] = 0.f;
    if (blk < 64) {
        const int bi = blk >> 3, bj = blk & 7;
        const int tx = tid & 63, r0 = (tid >> 6) * 16;
        #pragma unroll
        for (int m = 0; m < 16; ++m) {
            const int r = r0 + m;
            sm.t.tile[r][tx] = w1[(size_t)(bi * 64 + r) * 512 + bj * 64 + tx];
        }
        __syncthreads();
        #pragma unroll
        for (int m = 0; m < 16; ++m) {
            const int r = r0 + m;
            w1Tb[(size_t)(bj * 64 + r) * 512 + bi * 64 + tx] = f2bf(sm.t.tile[tx][r]);
        }
    }
    grid.sync();

    // ---- P1: h_ws[v][t] = relu(emb[v].w1[t] + b1[t]) (200 blocks) ---------
    {
        const int pair = blk >> 1, half = blk & 1;
        const int v0 = pair * 2, v1 = v0 + 1;
        {
            const float* __restrict__ x0 = emb + (size_t)v0 * E_;
            const float* __restrict__ x1 = emb + (size_t)v1 * E_;
            #pragma unroll
            for (int m = 0; m < 2; ++m) {
                const int k = tid + m * 256;
                sm.h.xi[2 * k]     = x0[k];
                sm.h.xi[2 * k + 1] = x1[k];
            }
        }
        __syncthreads();
        const int part = tid >> 6, quad = tid & 63;
        const int t0 = half * 256 + quad * 4, k0 = part * 128;
        float a0 = 0.f, a1 = 0.f, a2 = 0.f, a3 = 0.f;
        float c0 = 0.f, c1 = 0.f, c2 = 0.f, c3 = 0.f;
        const unsigned short* __restrict__ wp = w1Tb + (size_t)k0 * H_ + t0;
        const float2* __restrict__ xp = (const float2*)sm.h.xi + k0;
        #pragma unroll 4
        for (int i = 0; i < 128; ++i) {
            const uint2 wu = *(const uint2*)(wp + (size_t)i * H_);
            const float2 x = xp[i];
            const float w0 = __uint_as_float(wu.x << 16);
            const float w1v = __uint_as_float(wu.x & 0xffff0000u);
            const float w2v = __uint_as_float(wu.y << 16);
            const float w3v = __uint_as_float(wu.y & 0xffff0000u);
            a0 = fmaf(w0,  x.x, a0); a1 = fmaf(w1v, x.x, a1);
            a2 = fmaf(w2v, x.x, a2); a3 = fmaf(w3v, x.x, a3);
            c0 = fmaf(w0,  x.y, c0); c1 = fmaf(w1v, x.y, c1);
            c2 = fmaf(w2v, x.y, c2); c3 = fmaf(w3v, x.y, c3);
        }
        sm.h.part[part][quad][0] = a0; sm.h.part[part][quad][1] = a1;
        sm.h.part[part][quad][2] = a2; sm.h.part[part][quad][3] = a3;
        sm.h.part[part][quad][4] = c0; sm.h.part[part][quad][5] = c1;
        sm.h.part[part][quad][6] = c2; sm.h.part[part][quad][7] = c3;
        __syncthreads();
        {
            const int q2 = tid >> 2, r0 = tid & 3;
            const float s0 = (sm.h.part[0][q2][r0]     + sm.h.part[1][q2][r0])
                           + (sm.h.part[2][q2][r0]     + sm.h.part[3][q2][r0]);
            const float s1 = (sm.h.part[0][q2][r0 + 4] + sm.h.part[1][q2][r0 + 4])
                           + (sm.h.part[2][q2][r0 + 4] + sm.h.part[3][q2][r0 + 4]);
            const int t = half * 256 + tid;
            const float bb = b1[t];
            h_ws[(size_t)v0 * H_ + t] = fmaxf(s0 + bb, 0.f);
            h_ws[(size_t)v1 * H_ + t] = fmaxf(s1 + bb, 0.f);
        }
    }
    grid.sync();

    // ---- P2: em_table / w_table / emax (200 blocks, v = blk) --------------
    {
        const int v = blk;
        const int wave = tid >> 6, lane = tid & 63;
        const float* __restrict__ hrow = h_ws + (size_t)v * H_;
        for (int jj2 = 0; jj2 < 6; ++jj2) {
            const int jo = wave * 6 + jj2;
            float part = 0.f;
            #pragma unroll
            for (int m = 0; m < H_ / 64; ++m) {
                const int k = lane + m * 64;
                part = fmaf(hrow[k], w2[(size_t)jo * H_ + k], part);
            }
            #pragma unroll
            for (int off = 32; off; off >>= 1)
                part += __shfl_xor(part, off, 64);
            if (lane == 0) {
                float val = fmaxf(part + b2[jo], 0.f);
                if (v == 0 && jo == PAD_IDX) val += BIGV;
                sm.e.em_row[jo] = val;
            }
        }
        __syncthreads();
        if (tid < 32) {
            float x = (tid < T_) ? sm.e.em_row[tid] : -INFINITY;
            float mx = x;
            #pragma unroll
            for (int off = 16; off; off >>= 1)
                mx = fmaxf(mx, __shfl_xor(mx, off, 32));
            if (tid < T_) {
                em_table[v * T_ + tid] = x;
                w_table[v * T_ + tid]  = __expf(x - mx);
            }
            if (tid == 0) emax_arr[v] = mx;
        }
    }
    grid.sync();

    // ---- P3: crf (blocks 0..31; waves 0-1 chain, waves 2-3 gold) ----------
    if (blk < 32) {
        const int g = blk;
        for (int i = tid; i < V_ * T_ / 4; i += 256)
            ((float4*)sm.c.w_s)[i] = ((const float4*)w_table)[i];
        {   // tokens transposed: tok_s[s][n]
            const int bq = tid & 31, c = tid >> 3;   // unused pattern below
            (void)bq; (void)c;
        }
        {
            const int bq = tid & 31, c = tid >> 5;   // c in 0..7, 16 rows each
            const int* __restrict__ src = seq + (size_t)(g * 32 + bq) * S_ + c * 16;
            #pragma unroll
            for (int i = 0; i < 16; ++i)
                sm.c.tok_s[(c * 16 + i) * 32 + bq] = src[i];
        }
        if (tid < 32) sm.c.gp[tid] = 0.f;
        __syncthreads();

        if (tid < 128) {
            // ---------------- chain (R11, verified absmax 0.0) -------------
            const bool isF = (tid < 64);
            const int lane = tid & 63;
            const int n = lane & 31;
            const int h = lane >> 5;

            u32x4 A1p, A2p;
            {
                float a1e[8], a2e[8];
                #pragma unroll
                for (int j = 0; j < 8; ++j) {
                    const int k1 = 8 * h + j;
                    const int k2 = 16 + 8 * h + j;
                    float v1 = 0.f, v2 = 0.f;
                    if (n < T_) {
                        v1 = __expf(isF ? trans[k1 * T_ + n] : trans[n * T_ + k1]);
                        if (k2 < T_)
                            v2 = __expf(isF ? trans[k2 * T_ + n] : trans[n * T_ + k2]);
                    }
                    a1e[j] = v1; a2e[j] = v2;
                }
                #pragma unroll
                for (int r = 0; r < 4; ++r) {
                    A1p[r] = pkbf(a1e[2 * r], a1e[2 * r + 1]);
                    A2p[r] = pkbf(a2e[2 * r], a2e[2 * r + 1]);
                }
            }

            float logacc;
            u32x4 B1p, B2p;
            {
                const int tokI = sm.c.tok_s[(isF ? 0 : (S_ - 1)) * 32 + n];
                float q1[8], q2[8];
                if (isF) {
                    float e1[8], e2[8];
                    #pragma unroll
                    for (int j = 0; j < 8; ++j) { e1[j] = 0.f; e2[j] = 0.f; }
                    float mx = -INFINITY;
                    #pragma unroll
                    for (int j = 0; j < 8; ++j) {
                        const int r1 = 8 * h + j;
                        e1[j] = start_t[r1] + em_table[tokI * T_ + r1];
                        mx = fmaxf(mx, e1[j]);
                    }
                    if (h == 0) {
                        #pragma unroll
                        for (int j = 0; j < 8; ++j) {
                            const int r2 = 16 + j;
                            e2[j] = start_t[r2] + em_table[tokI * T_ + r2];
                            mx = fmaxf(mx, e2[j]);
                        }
                    }
                    mx = fmaxf(mx, __shfl_xor(mx, 32, 64));
                    #pragma unroll
                    for (int j = 0; j < 8; ++j) {
                        q1[j] = __expf(e1[j] - mx);
                        q2[j] = (h == 0) ? __expf(e2[j] - mx) : 0.f;
                    }
                    logacc = mx;
                } else {
                    #pragma unroll
                    for (int j = 0; j < 8; ++j) {
                        const int r1 = 8 * h + j;
                        q1[j] = sm.c.w_s[tokI * T_ + r1] * __expf(end_t[r1]);
                        const int r2 = 16 + j;
                        q2[j] = (h == 0) ? sm.c.w_s[tokI * T_ + r2] * __expf(end_t[r2]) : 0.f;
                    }
                    logacc = 0.f;
                }
                #pragma unroll
                for (int r = 0; r < 4; ++r) {
                    B1p[r] = pkbf(q1[2 * r], q1[2 * r + 1]);
                    B2p[r] = pkbf(q2[2 * r], q2[2 * r + 1]);
                }
            }

            const int dir  = isF ? 1 : -1;
            const int offi = isF ? 1 : (S_ - 2);

            float4 Wc0, Wc1, Wc2;
            {
                const int tk = sm.c.tok_s[offi * 32 + n];
                const float* wb = sm.c.w_s + tk * T_ + 4 * h;
                Wc0 = *(const float4*)(wb);
                Wc1 = *(const float4*)(wb + 8);
                Wc2 = *(const float4*)(wb + 16);
            }

            float d[12];
            for (int s = 1; s <= 63; ++s) {
                const int sn = (s < 63) ? (s + 1) : 63;
                const int tkN = sm.c.tok_s[(offi + dir * (sn - 1)) * 32 + n];
                const float* wbn = sm.c.w_s + tkN * T_ + 4 * h;
                const float4 Wn0 = *(const float4*)(wbn);
                const float4 Wn1 = *(const float4*)(wbn + 8);
                const float4 Wn2 = *(const float4*)(wbn + 16);

                facc16 acc;
                #pragma unroll
                for (int r = 0; r < 16; ++r) acc[r] = 0.f;
                acc = __builtin_amdgcn_mfma_f32_32x32x16_bf16(
                          __builtin_bit_cast(bf8frag, A2p),
                          __builtin_bit_cast(bf8frag, B2p), acc, 0, 0, 0);
                acc = __builtin_amdgcn_mfma_f32_32x32x16_bf16(
                          __builtin_bit_cast(bf8frag, A1p),
                          __builtin_bit_cast(bf8frag, B1p), acc, 0, 0, 0);

                d[0] = acc[0]*Wc0.x;  d[1] = acc[1]*Wc0.y;  d[2]  = acc[2]*Wc0.z;  d[3]  = acc[3]*Wc0.w;
                d[4] = acc[4]*Wc1.x;  d[5] = acc[5]*Wc1.y;  d[6]  = acc[6]*Wc1.z;  d[7]  = acc[7]*Wc1.w;
                d[8] = acc[8]*Wc2.x;  d[9] = acc[9]*Wc2.y;  d[10] = acc[10]*Wc2.z; d[11] = acc[11]*Wc2.w;

                if ((s & 15) == 0 || s == 63) {
                    float mx = d[0];
                    #pragma unroll
                    for (int r = 1; r < 12; ++r) mx = fmaxf(mx, d[r]);
                    mx = fmaxf(mx, __shfl_xor(mx, 32, 64));
                    const float inv = 1.0f / mx;
                    #pragma unroll
                    for (int r = 0; r < 12; ++r) d[r] *= inv;
                    logacc += __logf(mx);
                }

                const unsigned P0 = pkbf(d[0], d[1]),  P1 = pkbf(d[2], d[3]);
                const unsigned P2 = pkbf(d[4], d[5]),  P3 = pkbf(d[6], d[7]);
                const unsigned P4 = pkbf(d[8], d[9]),  P5 = pkbf(d[10], d[11]);
                const unsigned XP0 = (unsigned)__shfl_xor((int)P0, 32, 64);
                const unsigned XP1 = (unsigned)__shfl_xor((int)P1, 32, 64);
                const unsigned XP2 = (unsigned)__shfl_xor((int)P2, 32, 64);
                const unsigned XP3 = (unsigned)__shfl_xor((int)P3, 32, 64);
                const unsigned XP4 = (unsigned)__shfl_xor((int)P4, 32, 64);
                const unsigned XP5 = (unsigned)__shfl_xor((int)P5, 32, 64);
                B1p[0] = h ? XP2 : P0;  B1p[1] = h ? XP3 : P1;
                B1p[2] = h ? P2  : XP0; B1p[3] = h ? P3  : XP1;
                B2p[0] = h ? 0u  : P4;  B2p[1] = h ? 0u  : P5;
                B2p[2] = h ? 0u  : XP4; B2p[3] = h ? 0u  : XP5;

                Wc0 = Wn0; Wc1 = Wn1; Wc2 = Wn2;
            }

            if (!isF) {
                #pragma unroll
                for (int r = 0; r < 12; ++r) sm.c.meet[lane * 12 + r] = d[r];
                sm.c.logb[lane] = logacc;
            } else {
                // stash fwd state for after the barrier via registers:
                // (nothing to do — B frags & logacc live in registers)
            }
            // save for post-barrier use
            if (isF) { sm.c.meet[0] += 0.f; }  // no-op keep structure
            // fall through to barrier below with registers intact
            // (post-barrier final step executed under tid<64 guard)
            if (isF) {
                // keep B1p/B2p/A1p/A2p/logacc for final — they persist
            }
            __syncthreads();
            if (isF) {
                facc16 acc;
                #pragma unroll
                for (int r = 0; r < 16; ++r) acc[r] = 0.f;
                acc = __builtin_amdgcn_mfma_f32_32x32x16_bf16(
                          __builtin_bit_cast(bf8frag, A2p),
                          __builtin_bit_cast(bf8frag, B2p), acc, 0, 0, 0);
                acc = __builtin_amdgcn_mfma_f32_32x32x16_bf16(
                          __builtin_bit_cast(bf8frag, A1p),
                          __builtin_bit_cast(bf8frag, B1p), acc, 0, 0, 0);
                float dot = 0.f;
                #pragma unroll
                for (int r = 0; r < 12; ++r)
                    dot = fmaf(acc[r], sm.c.meet[lane * 12 + r], dot);
                dot += __shfl_xor(dot, 32, 64);
                const float denom = logacc + sm.c.logb[lane] + __logf(dot);
                float val = 0.f;
                if (h == 0)
                    val = (denom - sm.c.gp[n]) * (1.0f / (float)B_);
                #pragma unroll
                for (int off = 32; off; off >>= 1)
                    val += __shfl_xor(val, off, 64);
                if (lane == 0) atomicAdd(out, val);
            }
        } else {
            // ---------------- gold (waves 2-3), exact R11 math -------------
            const int t2 = tid - 128;
            const int n = t2 & 31;          // batch in group
            const int r = t2 >> 5;          // quarter 0..3
            const int b = g * 32 + n;
            const int* __restrict__ lrow = labels + (size_t)b * S_;
            float gp = 0.f;
            for (int i = 0; i < 32; ++i) {
                const int s = r * 32 + i;
                const int tk = sm.c.tok_s[s * 32 + n];
                const int ls = lrow[s];
                gp += em_table[tk * T_ + ls];
                if (s >= 1) gp -= emax_arr[tk];
                if (s < S_ - 1) gp += trans[ls * T_ + lrow[s + 1]];
                if (s == 0) gp += start_t[ls];
                if (s == S_ - 1) gp += end_t[ls];
            }
            atomicAdd(&sm.c.gp[n], gp);
            __syncthreads();   // pairs with the chain waves' barrier
        }
    }
}

// ---------------------------------------------------------------------------
extern "C" void kernel_launch(void* const* d_in, const int* in_sizes, int n_in,
                              void* d_out, int out_size, void* d_ws, size_t ws_size,
                              hipStream_t stream) {
    const int*   seq     = (const int*)d_in[0];
    const int*   labels  = (const int*)d_in[1];
    // d_in[2] true_lengths: unused by the reference forward
    const float* emb     = (const float*)d_in[3];
    const float* w1      = (const float*)d_in[4];
    const float* b1      = (const float*)d_in[5];
    const float* w2      = (const float*)d_in[6];
    const float* b2      = (const float*)d_in[7];
    const float* start_t = (const float*)d_in[8];
    const float* end_t   = (const float*)d_in[9];
    const float* trans   = (const float*)d_in[10];

    float* ws            = (float*)d_ws;
    unsigned short* w1Tb = (unsigned short*)d_ws;
    float* h_ws          = ws + OFF_H;
    float* em_table      = ws + OFF_EM;
    float* w_table       = ws + OFF_W;
    float* emax_arr      = ws + OFF_MX;
    float* out           = (float*)d_out;

    void* kargs[] = {
        (void*)&seq, (void*)&labels, (void*)&emb, (void*)&w1, (void*)&b1,
        (void*)&w2, (void*)&b2, (void*)&start_t, (void*)&end_t, (void*)&trans,
        (void*)&w1Tb, (void*)&h_ws, (void*)&em_table, (void*)&w_table,
        (void*)&emax_arr, (void*)&out
    };
    hipLaunchCooperativeKernel((const void*)fused_kernel, dim3(200), dim3(256),
                               kargs, 0, stream);
}

// Round 13
// 124.534 us; speedup vs baseline: 1.5742x; 1.5742x over previous
//
#include <hip/hip_runtime.h>
#include <math.h>

#define PAD_IDX 0
#define BIGV 10000.0f
constexpr int B_ = 1024, S_ = 128, V_ = 200, E_ = 512, H_ = 512, T_ = 24;

// ws layout (float offsets): w1Tb bf16 @0 (131072 floats), tables above.
constexpr int OFF_EM = 262144;   // em_tab [200][24]
constexpr int OFF_W  = 267008;   // w_tab  [200][24]
constexpr int OFF_MX = 271872;   // emax   [200]

typedef __attribute__((ext_vector_type(8)))  short    bf8frag;   // 8 bf16
typedef __attribute__((ext_vector_type(16))) float    facc16;    // MFMA C/D
typedef __attribute__((ext_vector_type(4)))  unsigned u32x4;

__device__ __forceinline__ unsigned short f2bf(float f) {
    unsigned u = __float_as_uint(f);
    u += 0x7fffu + ((u >> 16) & 1u);
    return (unsigned short)(u >> 16);
}
__device__ __forceinline__ unsigned pkbf(float lo, float hi) {
    const unsigned a = __float_as_uint(lo), b = __float_as_uint(hi);
    return ((a + 0x8000u) >> 16) | ((b + 0x8000u) & 0xffff0000u);
}

// ---------------------------------------------------------------------------
// Kernel T: transpose w1 -> bf16 (proven). Zeroes out[0] for crf atomics.
// ---------------------------------------------------------------------------
__global__ __launch_bounds__(256) void transpose_kernel(
    const float* __restrict__ w1, unsigned short* __restrict__ w1Tb,
    float* __restrict__ out)
{
    __shared__ float tile[64][65];
    const int bi = blockIdx.x >> 3, bj = blockIdx.x & 7;
    const int tx = threadIdx.x & 63, r0 = (threadIdx.x >> 6) * 16;
    if (blockIdx.x == 0 && threadIdx.x == 0) out[0] = 0.f;
    #pragma unroll
    for (int m = 0; m < 16; ++m) {
        const int r = r0 + m;
        tile[r][tx] = w1[(size_t)(bi * 64 + r) * 512 + bj * 64 + tx];
    }
    __syncthreads();
    #pragma unroll
    for (int m = 0; m < 16; ++m) {
        const int r = r0 + m;
        w1Tb[(size_t)(bj * 64 + r) * 512 + bi * 64 + tx] = f2bf(tile[tx][r]);
    }
}

// ---------------------------------------------------------------------------
// Kernel M (R13): h + emis FUSED. One block = one v-pair, FULL 512 rows.
// Phase h: thread (part in 0..1, tq in 0..127) accumulates t-quad tq*4..+3
// over k in [part*256, part*256+256) for both v's (8 indep FMA chains,
// coalesced bf16 dwordx2 w-loads, LDS x broadcast). h stays in LDS — no
// global round-trip (R11 wrote h_ws to HBM and re-read it in emis).
// Phase emis: 4 waves x 12 of the 48 (2v x 24t) outputs, split-K-64 + shfl.
// Phase 3: row max + exp-normalized w_table (two 32-lane groups).
// ---------------------------------------------------------------------------
__global__ __launch_bounds__(256) void mlp_kernel(
    const float* __restrict__ emb, const unsigned short* __restrict__ w1Tb,
    const float* __restrict__ b1, const float* __restrict__ w2,
    const float* __restrict__ b2, float* __restrict__ em_table,
    float* __restrict__ w_table, float* __restrict__ emax_arr)
{
    __shared__ float xi[2 * E_];           // interleaved {x0[k], x1[k]}
    __shared__ float part_s[2][128][8];    // [k-part][t-quad][4t x 2v]
    __shared__ float hs[2][H_];            // h rows for v0, v1
    __shared__ float em_row[2][32];
    const int v0 = blockIdx.x * 2, v1 = v0 + 1;
    const int tid = threadIdx.x;

    {
        const float* __restrict__ x0 = emb + (size_t)v0 * E_;
        const float* __restrict__ x1 = emb + (size_t)v1 * E_;
        #pragma unroll
        for (int m = 0; m < 2; ++m) {
            const int k = tid + m * 256;
            xi[2 * k]     = x0[k];
            xi[2 * k + 1] = x1[k];
        }
    }
    __syncthreads();

    // ---- phase h ----
    {
        const int part = tid >> 7;         // 0..1 (k half)
        const int tq   = tid & 127;        // 0..127 (t quad)
        const int t0 = tq * 4, k0 = part * 256;
        float a0 = 0.f, a1 = 0.f, a2 = 0.f, a3 = 0.f;
        float c0 = 0.f, c1 = 0.f, c2 = 0.f, c3 = 0.f;
        const unsigned short* __restrict__ wp = w1Tb + (size_t)k0 * H_ + t0;
        const float2* __restrict__ xp = (const float2*)xi + k0;
        #pragma unroll 4
        for (int i = 0; i < 256; ++i) {
            const uint2 wu = *(const uint2*)(wp + (size_t)i * H_);
            const float2 x = xp[i];
            const float w0 = __uint_as_float(wu.x << 16);
            const float w1v = __uint_as_float(wu.x & 0xffff0000u);
            const float w2v = __uint_as_float(wu.y << 16);
            const float w3v = __uint_as_float(wu.y & 0xffff0000u);
            a0 = fmaf(w0,  x.x, a0); a1 = fmaf(w1v, x.x, a1);
            a2 = fmaf(w2v, x.x, a2); a3 = fmaf(w3v, x.x, a3);
            c0 = fmaf(w0,  x.y, c0); c1 = fmaf(w1v, x.y, c1);
            c2 = fmaf(w2v, x.y, c2); c3 = fmaf(w3v, x.y, c3);
        }
        part_s[part][tq][0] = a0; part_s[part][tq][1] = a1;
        part_s[part][tq][2] = a2; part_s[part][tq][3] = a3;
        part_s[part][tq][4] = c0; part_s[part][tq][5] = c1;
        part_s[part][tq][6] = c2; part_s[part][tq][7] = c3;
    }
    __syncthreads();
    {
        #pragma unroll
        for (int m = 0; m < 2; ++m) {
            const int t = tid + m * 256;
            const int q2 = t >> 2, r = t & 3;
            const float s0 = part_s[0][q2][r]     + part_s[1][q2][r];
            const float s1 = part_s[0][q2][r + 4] + part_s[1][q2][r + 4];
            const float bb = b1[t];
            hs[0][t] = fmaxf(s0 + bb, 0.f);
            hs[1][t] = fmaxf(s1 + bb, 0.f);
        }
    }
    __syncthreads();

    // ---- phase emis: 48 outputs over 4 waves ----
    {
        const int wave = tid >> 6, lane = tid & 63;
        const int vsel = wave >> 1;                  // v0 or v1
        const float* __restrict__ hrow = hs[vsel];
        for (int jj2 = 0; jj2 < 12; ++jj2) {
            const int j = (wave & 1) * 12 + jj2;     // 0..23
            float part = 0.f;
            #pragma unroll
            for (int m = 0; m < H_ / 64; ++m) {
                const int k = lane + m * 64;
                part = fmaf(hrow[k], w2[(size_t)j * H_ + k], part);
            }
            #pragma unroll
            for (int off = 32; off; off >>= 1)
                part += __shfl_xor(part, off, 64);
            if (lane == 0) {
                float val = fmaxf(part + b2[j], 0.f);
                if (v0 == 0 && vsel == 0 && j == PAD_IDX) val += BIGV;
                em_row[vsel][j] = val;
            }
        }
    }
    __syncthreads();

    // ---- phase 3: per-v row max + normalized tables (2 groups of 32) ----
    if (tid < 64) {
        const int grp = tid >> 5, j = tid & 31;
        const int v = v0 + grp;
        float x = (j < T_) ? em_row[grp][j] : -INFINITY;
        float mx = x;
        #pragma unroll
        for (int off = 16; off; off >>= 1)
            mx = fmaxf(mx, __shfl_xor(mx, off, 32));
        if (j < T_) {
            em_table[v * T_ + j] = x;
            w_table[v * T_ + j]  = __expf(x - mx);
        }
        if (j == 0) emax_arr[v] = mx;
    }
}

// ---------------------------------------------------------------------------
// Kernel B (R13): crf + gold fused (plain kernel; structure = R12 P3 which
// passed absmax 0.0). 32 blocks x 256 threads: waves 0-1 = MFMA fwd/bwd
// meet-in-middle chain (R11 math), waves 2-3 = gold path, concurrent.
// ---------------------------------------------------------------------------
__global__ __launch_bounds__(256) void crf_kernel(
    const int* __restrict__ seq, const int* __restrict__ labels,
    const float* __restrict__ start_t, const float* __restrict__ end_t,
    const float* __restrict__ trans, const float* __restrict__ em_table,
    const float* __restrict__ w_table, const float* __restrict__ emax_arr,
    float* __restrict__ out)
{
    __shared__ __align__(16) float w_s[V_ * T_];
    __shared__ int   tok_s[S_ * 32];
    __shared__ float meet_s[64 * 12];
    __shared__ float logb_s[64];
    __shared__ float gp_s[32];
    const int tid = threadIdx.x;
    const int g = blockIdx.x;

    for (int i = tid; i < V_ * T_ / 4; i += 256)
        ((float4*)w_s)[i] = ((const float4*)w_table)[i];
    {
        const int bq = tid & 31, c = tid >> 5;
        const int* __restrict__ src = seq + (size_t)(g * 32 + bq) * S_ + c * 16;
        #pragma unroll
        for (int i = 0; i < 16; ++i)
            tok_s[(c * 16 + i) * 32 + bq] = src[i];
    }
    if (tid < 32) gp_s[tid] = 0.f;
    __syncthreads();

    if (tid < 128) {
        // -------- chain (R11 math, verified absmax 0.0) --------
        const bool isF = (tid < 64);
        const int lane = tid & 63;
        const int n = lane & 31;
        const int h = lane >> 5;

        u32x4 A1p, A2p;
        {
            float a1e[8], a2e[8];
            #pragma unroll
            for (int j = 0; j < 8; ++j) {
                const int k1 = 8 * h + j;
                const int k2 = 16 + 8 * h + j;
                float v1 = 0.f, v2 = 0.f;
                if (n < T_) {
                    v1 = __expf(isF ? trans[k1 * T_ + n] : trans[n * T_ + k1]);
                    if (k2 < T_)
                        v2 = __expf(isF ? trans[k2 * T_ + n] : trans[n * T_ + k2]);
                }
                a1e[j] = v1; a2e[j] = v2;
            }
            #pragma unroll
            for (int r = 0; r < 4; ++r) {
                A1p[r] = pkbf(a1e[2 * r], a1e[2 * r + 1]);
                A2p[r] = pkbf(a2e[2 * r], a2e[2 * r + 1]);
            }
        }

        float logacc;
        u32x4 B1p, B2p;
        {
            const int tokI = tok_s[(isF ? 0 : (S_ - 1)) * 32 + n];
            float q1[8], q2[8];
            if (isF) {
                float e1[8], e2[8];
                #pragma unroll
                for (int j = 0; j < 8; ++j) { e1[j] = 0.f; e2[j] = 0.f; }
                float mx = -INFINITY;
                #pragma unroll
                for (int j = 0; j < 8; ++j) {
                    const int r1 = 8 * h + j;
                    e1[j] = start_t[r1] + em_table[tokI * T_ + r1];
                    mx = fmaxf(mx, e1[j]);
                }
                if (h == 0) {
                    #pragma unroll
                    for (int j = 0; j < 8; ++j) {
                        const int r2 = 16 + j;
                        e2[j] = start_t[r2] + em_table[tokI * T_ + r2];
                        mx = fmaxf(mx, e2[j]);
                    }
                }
                mx = fmaxf(mx, __shfl_xor(mx, 32, 64));
                #pragma unroll
                for (int j = 0; j < 8; ++j) {
                    q1[j] = __expf(e1[j] - mx);
                    q2[j] = (h == 0) ? __expf(e2[j] - mx) : 0.f;
                }
                logacc = mx;
            } else {
                #pragma unroll
                for (int j = 0; j < 8; ++j) {
                    const int r1 = 8 * h + j;
                    q1[j] = w_s[tokI * T_ + r1] * __expf(end_t[r1]);
                    const int r2 = 16 + j;
                    q2[j] = (h == 0) ? w_s[tokI * T_ + r2] * __expf(end_t[r2]) : 0.f;
                }
                logacc = 0.f;
            }
            #pragma unroll
            for (int r = 0; r < 4; ++r) {
                B1p[r] = pkbf(q1[2 * r], q1[2 * r + 1]);
                B2p[r] = pkbf(q2[2 * r], q2[2 * r + 1]);
            }
        }

        const int dir  = isF ? 1 : -1;
        const int offi = isF ? 1 : (S_ - 2);

        float4 Wc0, Wc1, Wc2;
        {
            const int tk = tok_s[offi * 32 + n];
            const float* wb = w_s + tk * T_ + 4 * h;
            Wc0 = *(const float4*)(wb);
            Wc1 = *(const float4*)(wb + 8);
            Wc2 = *(const float4*)(wb + 16);
        }

        float d[12];
        for (int s = 1; s <= 63; ++s) {
            const int sn = (s < 63) ? (s + 1) : 63;
            const int tkN = tok_s[(offi + dir * (sn - 1)) * 32 + n];
            const float* wbn = w_s + tkN * T_ + 4 * h;
            const float4 Wn0 = *(const float4*)(wbn);
            const float4 Wn1 = *(const float4*)(wbn + 8);
            const float4 Wn2 = *(const float4*)(wbn + 16);

            facc16 acc;
            #pragma unroll
            for (int r = 0; r < 16; ++r) acc[r] = 0.f;
            acc = __builtin_amdgcn_mfma_f32_32x32x16_bf16(
                      __builtin_bit_cast(bf8frag, A2p),
                      __builtin_bit_cast(bf8frag, B2p), acc, 0, 0, 0);
            acc = __builtin_amdgcn_mfma_f32_32x32x16_bf16(
                      __builtin_bit_cast(bf8frag, A1p),
                      __builtin_bit_cast(bf8frag, B1p), acc, 0, 0, 0);

            d[0] = acc[0]*Wc0.x;  d[1] = acc[1]*Wc0.y;  d[2]  = acc[2]*Wc0.z;  d[3]  = acc[3]*Wc0.w;
            d[4] = acc[4]*Wc1.x;  d[5] = acc[5]*Wc1.y;  d[6]  = acc[6]*Wc1.z;  d[7]  = acc[7]*Wc1.w;
            d[8] = acc[8]*Wc2.x;  d[9] = acc[9]*Wc2.y;  d[10] = acc[10]*Wc2.z; d[11] = acc[11]*Wc2.w;

            if ((s & 15) == 0 || s == 63) {
                float mx = d[0];
                #pragma unroll
                for (int r = 1; r < 12; ++r) mx = fmaxf(mx, d[r]);
                mx = fmaxf(mx, __shfl_xor(mx, 32, 64));
                const float inv = 1.0f / mx;
                #pragma unroll
                for (int r = 0; r < 12; ++r) d[r] *= inv;
                logacc += __logf(mx);
            }

            const unsigned P0 = pkbf(d[0], d[1]),  P1 = pkbf(d[2], d[3]);
            const unsigned P2 = pkbf(d[4], d[5]),  P3 = pkbf(d[6], d[7]);
            const unsigned P4 = pkbf(d[8], d[9]),  P5 = pkbf(d[10], d[11]);
            const unsigned XP0 = (unsigned)__shfl_xor((int)P0, 32, 64);
            const unsigned XP1 = (unsigned)__shfl_xor((int)P1, 32, 64);
            const unsigned XP2 = (unsigned)__shfl_xor((int)P2, 32, 64);
            const unsigned XP3 = (unsigned)__shfl_xor((int)P3, 32, 64);
            const unsigned XP4 = (unsigned)__shfl_xor((int)P4, 32, 64);
            const unsigned XP5 = (unsigned)__shfl_xor((int)P5, 32, 64);
            B1p[0] = h ? XP2 : P0;  B1p[1] = h ? XP3 : P1;
            B1p[2] = h ? P2  : XP0; B1p[3] = h ? P3  : XP1;
            B2p[0] = h ? 0u  : P4;  B2p[1] = h ? 0u  : P5;
            B2p[2] = h ? 0u  : XP4; B2p[3] = h ? 0u  : XP5;

            Wc0 = Wn0; Wc1 = Wn1; Wc2 = Wn2;
        }

        if (!isF) {
            #pragma unroll
            for (int r = 0; r < 12; ++r) meet_s[lane * 12 + r] = d[r];
            logb_s[lane] = logacc;
        }
        __syncthreads();
        if (isF) {
            facc16 acc;
            #pragma unroll
            for (int r = 0; r < 16; ++r) acc[r] = 0.f;
            acc = __builtin_amdgcn_mfma_f32_32x32x16_bf16(
                      __builtin_bit_cast(bf8frag, A2p),
                      __builtin_bit_cast(bf8frag, B2p), acc, 0, 0, 0);
            acc = __builtin_amdgcn_mfma_f32_32x32x16_bf16(
                      __builtin_bit_cast(bf8frag, A1p),
                      __builtin_bit_cast(bf8frag, B1p), acc, 0, 0, 0);
            float dot = 0.f;
            #pragma unroll
            for (int r = 0; r < 12; ++r)
                dot = fmaf(acc[r], meet_s[lane * 12 + r], dot);
            dot += __shfl_xor(dot, 32, 64);
            const float denom = logacc + logb_s[lane] + __logf(dot);
            float val = 0.f;
            if (h == 0)
                val = (denom - gp_s[n]) * (1.0f / (float)B_);
            #pragma unroll
            for (int off = 32; off; off >>= 1)
                val += __shfl_xor(val, off, 64);
            if (lane == 0) atomicAdd(out, val);
        }
    } else {
        // -------- gold (waves 2-3), exact verified math --------
        const int t2 = tid - 128;
        const int n = t2 & 31;
        const int r = t2 >> 5;
        const int b = g * 32 + n;
        const int* __restrict__ lrow = labels + (size_t)b * S_;
        float gp = 0.f;
        for (int i = 0; i < 32; ++i) {
            const int s = r * 32 + i;
            const int tk = tok_s[s * 32 + n];
            const int ls = lrow[s];
            gp += em_table[tk * T_ + ls];
            if (s >= 1) gp -= emax_arr[tk];
            if (s < S_ - 1) gp += trans[ls * T_ + lrow[s + 1]];
            if (s == 0) gp += start_t[ls];
            if (s == S_ - 1) gp += end_t[ls];
        }
        atomicAdd(&gp_s[n], gp);
        __syncthreads();   // pairs with the chain waves' barrier
    }
}

// ---------------------------------------------------------------------------
extern "C" void kernel_launch(void* const* d_in, const int* in_sizes, int n_in,
                              void* d_out, int out_size, void* d_ws, size_t ws_size,
                              hipStream_t stream) {
    const int*   seq     = (const int*)d_in[0];
    const int*   labels  = (const int*)d_in[1];
    // d_in[2] true_lengths: unused by the reference forward
    const float* emb     = (const float*)d_in[3];
    const float* w1      = (const float*)d_in[4];
    const float* b1      = (const float*)d_in[5];
    const float* w2      = (const float*)d_in[6];
    const float* b2      = (const float*)d_in[7];
    const float* start_t = (const float*)d_in[8];
    const float* end_t   = (const float*)d_in[9];
    const float* trans   = (const float*)d_in[10];

    float* ws            = (float*)d_ws;
    unsigned short* w1Tb = (unsigned short*)d_ws;
    float* em_table      = ws + OFF_EM;
    float* w_table       = ws + OFF_W;
    float* emax_arr      = ws + OFF_MX;
    float* out           = (float*)d_out;

    transpose_kernel<<<64, 256, 0, stream>>>(w1, w1Tb, out);
    mlp_kernel<<<V_ / 2, 256, 0, stream>>>(emb, w1Tb, b1, w2, b2,
                                           em_table, w_table, emax_arr);
    crf_kernel<<<B_ / 32, 256, 0, stream>>>(seq, labels, start_t, end_t, trans,
                                            em_table, w_table, emax_arr, out);
}

// Round 14
// 117.555 us; speedup vs baseline: 1.6677x; 1.0594x over previous
//
#include <hip/hip_runtime.h>
#include <math.h>

#define PAD_IDX 0
#define BIGV 10000.0f
constexpr int B_ = 1024, S_ = 128, V_ = 200, E_ = 512, H_ = 512, T_ = 24;

// ws layout (float offsets):
constexpr int OFF_H  = 262144;   // h_ws   [200][512]
constexpr int OFF_EM = 364544;   // em_tab [200][24]
constexpr int OFF_W  = 369344;   // w_tab  [200][24]
constexpr int OFF_MX = 374144;   // emax   [200]

typedef __attribute__((ext_vector_type(8)))  short    bf8frag;   // 8 bf16
typedef __attribute__((ext_vector_type(16))) float    facc16;    // MFMA C/D
typedef __attribute__((ext_vector_type(4)))  unsigned u32x4;

__device__ __forceinline__ unsigned short f2bf(float f) {
    unsigned u = __float_as_uint(f);
    u += 0x7fffu + ((u >> 16) & 1u);
    return (unsigned short)(u >> 16);
}
__device__ __forceinline__ unsigned pkbf(float lo, float hi) {
    const unsigned a = __float_as_uint(lo), b = __float_as_uint(hi);
    return ((a + 0x8000u) >> 16) | ((b + 0x8000u) & 0xffff0000u);
}

// ---------------------------------------------------------------------------
// Kernel T: transpose w1 -> bf16 (proven R11). Zeroes out[0].
// ---------------------------------------------------------------------------
__global__ __launch_bounds__(256) void transpose_kernel(
    const float* __restrict__ w1, unsigned short* __restrict__ w1Tb,
    float* __restrict__ out)
{
    __shared__ float tile[64][65];
    const int bi = blockIdx.x >> 3, bj = blockIdx.x & 7;
    const int tx = threadIdx.x & 63, r0 = (threadIdx.x >> 6) * 16;
    if (blockIdx.x == 0 && threadIdx.x == 0) out[0] = 0.f;
    #pragma unroll
    for (int m = 0; m < 16; ++m) {
        const int r = r0 + m;
        tile[r][tx] = w1[(size_t)(bi * 64 + r) * 512 + bj * 64 + tx];
    }
    __syncthreads();
    #pragma unroll
    for (int m = 0; m < 16; ++m) {
        const int r = r0 + m;
        w1Tb[(size_t)(bj * 64 + r) * 512 + bi * 64 + tx] = f2bf(tile[tx][r]);
    }
}

// ---------------------------------------------------------------------------
// Kernel A1: h_ws (proven R11: 200 blocks x 128-iter — faster than R13's
// 100-block merge in this latency-bound regime).
// ---------------------------------------------------------------------------
__global__ __launch_bounds__(256) void h_kernel(
    const float* __restrict__ emb, const unsigned short* __restrict__ w1Tb,
    const float* __restrict__ b1, float* __restrict__ h_ws)
{
    __shared__ float xi[2 * E_];
    __shared__ float part_s[4][64][8];
    const int pair = blockIdx.x >> 1, half = blockIdx.x & 1;
    const int v0 = pair * 2, v1 = v0 + 1;
    const int tid = threadIdx.x;
    {
        const float* __restrict__ x0 = emb + (size_t)v0 * E_;
        const float* __restrict__ x1 = emb + (size_t)v1 * E_;
        #pragma unroll
        for (int m = 0; m < 2; ++m) {
            const int k = tid + m * 256;
            xi[2 * k]     = x0[k];
            xi[2 * k + 1] = x1[k];
        }
    }
    __syncthreads();
    const int part = tid >> 6, quad = tid & 63;
    const int t0 = half * 256 + quad * 4, k0 = part * 128;
    float a0 = 0.f, a1 = 0.f, a2 = 0.f, a3 = 0.f;
    float c0 = 0.f, c1 = 0.f, c2 = 0.f, c3 = 0.f;
    const unsigned short* __restrict__ wp = w1Tb + (size_t)k0 * H_ + t0;
    const float2* __restrict__ xp = (const float2*)xi + k0;
    #pragma unroll 4
    for (int i = 0; i < 128; ++i) {
        const uint2 wu = *(const uint2*)(wp + (size_t)i * H_);
        const float2 x = xp[i];
        const float w0 = __uint_as_float(wu.x << 16);
        const float w1v = __uint_as_float(wu.x & 0xffff0000u);
        const float w2v = __uint_as_float(wu.y << 16);
        const float w3v = __uint_as_float(wu.y & 0xffff0000u);
        a0 = fmaf(w0,  x.x, a0); a1 = fmaf(w1v, x.x, a1);
        a2 = fmaf(w2v, x.x, a2); a3 = fmaf(w3v, x.x, a3);
        c0 = fmaf(w0,  x.y, c0); c1 = fmaf(w1v, x.y, c1);
        c2 = fmaf(w2v, x.y, c2); c3 = fmaf(w3v, x.y, c3);
    }
    part_s[part][quad][0] = a0; part_s[part][quad][1] = a1;
    part_s[part][quad][2] = a2; part_s[part][quad][3] = a3;
    part_s[part][quad][4] = c0; part_s[part][quad][5] = c1;
    part_s[part][quad][6] = c2; part_s[part][quad][7] = c3;
    __syncthreads();
    {
        const int q2 = tid >> 2, r0 = tid & 3;
        const float s0 = (part_s[0][q2][r0]     + part_s[1][q2][r0])
                       + (part_s[2][q2][r0]     + part_s[3][q2][r0]);
        const float s1 = (part_s[0][q2][r0 + 4] + part_s[1][q2][r0 + 4])
                       + (part_s[2][q2][r0 + 4] + part_s[3][q2][r0 + 4]);
        const int t = half * 256 + tid;
        const float bb = b1[t];
        h_ws[(size_t)v0 * H_ + t] = fmaxf(s0 + bb, 0.f);
        h_ws[(size_t)v1 * H_ + t] = fmaxf(s1 + bb, 0.f);
    }
}

// ---------------------------------------------------------------------------
// Kernel A2: em_table / w_table / emax (proven R11).
// ---------------------------------------------------------------------------
__global__ __launch_bounds__(256) void emis_kernel(
    const float* __restrict__ h_ws, const float* __restrict__ w2,
    const float* __restrict__ b2, float* __restrict__ em_table,
    float* __restrict__ w_table, float* __restrict__ emax_arr)
{
    __shared__ float em_row[32];
    const int v = blockIdx.x;
    const int t = threadIdx.x;
    const int wave = t >> 6, lane = t & 63;
    const float* __restrict__ hrow = h_ws + (size_t)v * H_;
    for (int jj2 = 0; jj2 < 6; ++jj2) {
        const int jo = wave * 6 + jj2;
        float part = 0.f;
        #pragma unroll
        for (int m = 0; m < H_ / 64; ++m) {
            const int k = lane + m * 64;
            part = fmaf(hrow[k], w2[(size_t)jo * H_ + k], part);
        }
        #pragma unroll
        for (int off = 32; off; off >>= 1)
            part += __shfl_xor(part, off, 64);
        if (lane == 0) {
            float val = fmaxf(part + b2[jo], 0.f);
            if (v == 0 && jo == PAD_IDX) val += BIGV;
            em_row[jo] = val;
        }
    }
    __syncthreads();
    if (t < 32) {
        float x = (t < T_) ? em_row[t] : -INFINITY;
        float mx = x;
        #pragma unroll
        for (int off = 16; off; off >>= 1)
            mx = fmaxf(mx, __shfl_xor(mx, off, 32));
        if (t < T_) {
            em_table[v * T_ + t] = x;
            w_table[v * T_ + t]  = __expf(x - mx);
        }
        if (t == 0) emax_arr[v] = mx;
    }
}

// ---------------------------------------------------------------------------
// Kernel B (R14): crf + gold fused (R13 structure, absmax 0.0) with one
// micro-opt: the two MFMAs per step go to INDEPENDENT accumulators summed
// at the W-multiply — breaks MFMA->MFMA serialization on the exposed
// latency chain (d = (accA+accB)*W; same math, different f32 add order).
// ---------------------------------------------------------------------------
__global__ __launch_bounds__(256) void crf_kernel(
    const int* __restrict__ seq, const int* __restrict__ labels,
    const float* __restrict__ start_t, const float* __restrict__ end_t,
    const float* __restrict__ trans, const float* __restrict__ em_table,
    const float* __restrict__ w_table, const float* __restrict__ emax_arr,
    float* __restrict__ out)
{
    __shared__ __align__(16) float w_s[V_ * T_];
    __shared__ int   tok_s[S_ * 32];
    __shared__ float meet_s[64 * 12];
    __shared__ float logb_s[64];
    __shared__ float gp_s[32];
    const int tid = threadIdx.x;
    const int g = blockIdx.x;

    for (int i = tid; i < V_ * T_ / 4; i += 256)
        ((float4*)w_s)[i] = ((const float4*)w_table)[i];
    {
        const int bq = tid & 31, c = tid >> 5;
        const int* __restrict__ src = seq + (size_t)(g * 32 + bq) * S_ + c * 16;
        #pragma unroll
        for (int i = 0; i < 16; ++i)
            tok_s[(c * 16 + i) * 32 + bq] = src[i];
    }
    if (tid < 32) gp_s[tid] = 0.f;
    __syncthreads();

    if (tid < 128) {
        // -------- chain (R11 math, verified absmax 0.0) --------
        const bool isF = (tid < 64);
        const int lane = tid & 63;
        const int n = lane & 31;
        const int h = lane >> 5;

        u32x4 A1p, A2p;
        {
            float a1e[8], a2e[8];
            #pragma unroll
            for (int j = 0; j < 8; ++j) {
                const int k1 = 8 * h + j;
                const int k2 = 16 + 8 * h + j;
                float v1 = 0.f, v2 = 0.f;
                if (n < T_) {
                    v1 = __expf(isF ? trans[k1 * T_ + n] : trans[n * T_ + k1]);
                    if (k2 < T_)
                        v2 = __expf(isF ? trans[k2 * T_ + n] : trans[n * T_ + k2]);
                }
                a1e[j] = v1; a2e[j] = v2;
            }
            #pragma unroll
            for (int r = 0; r < 4; ++r) {
                A1p[r] = pkbf(a1e[2 * r], a1e[2 * r + 1]);
                A2p[r] = pkbf(a2e[2 * r], a2e[2 * r + 1]);
            }
        }

        float logacc;
        u32x4 B1p, B2p;
        {
            const int tokI = tok_s[(isF ? 0 : (S_ - 1)) * 32 + n];
            float q1[8], q2[8];
            if (isF) {
                float e1[8], e2[8];
                #pragma unroll
                for (int j = 0; j < 8; ++j) { e1[j] = 0.f; e2[j] = 0.f; }
                float mx = -INFINITY;
                #pragma unroll
                for (int j = 0; j < 8; ++j) {
                    const int r1 = 8 * h + j;
                    e1[j] = start_t[r1] + em_table[tokI * T_ + r1];
                    mx = fmaxf(mx, e1[j]);
                }
                if (h == 0) {
                    #pragma unroll
                    for (int j = 0; j < 8; ++j) {
                        const int r2 = 16 + j;
                        e2[j] = start_t[r2] + em_table[tokI * T_ + r2];
                        mx = fmaxf(mx, e2[j]);
                    }
                }
                mx = fmaxf(mx, __shfl_xor(mx, 32, 64));
                #pragma unroll
                for (int j = 0; j < 8; ++j) {
                    q1[j] = __expf(e1[j] - mx);
                    q2[j] = (h == 0) ? __expf(e2[j] - mx) : 0.f;
                }
                logacc = mx;
            } else {
                #pragma unroll
                for (int j = 0; j < 8; ++j) {
                    const int r1 = 8 * h + j;
                    q1[j] = w_s[tokI * T_ + r1] * __expf(end_t[r1]);
                    const int r2 = 16 + j;
                    q2[j] = (h == 0) ? w_s[tokI * T_ + r2] * __expf(end_t[r2]) : 0.f;
                }
                logacc = 0.f;
            }
            #pragma unroll
            for (int r = 0; r < 4; ++r) {
                B1p[r] = pkbf(q1[2 * r], q1[2 * r + 1]);
                B2p[r] = pkbf(q2[2 * r], q2[2 * r + 1]);
            }
        }

        const int dir  = isF ? 1 : -1;
        const int offi = isF ? 1 : (S_ - 2);

        float4 Wc0, Wc1, Wc2;
        {
            const int tk = tok_s[offi * 32 + n];
            const float* wb = w_s + tk * T_ + 4 * h;
            Wc0 = *(const float4*)(wb);
            Wc1 = *(const float4*)(wb + 8);
            Wc2 = *(const float4*)(wb + 16);
        }

        float d[12];
        for (int s = 1; s <= 63; ++s) {
            const int sn = (s < 63) ? (s + 1) : 63;
            const int tkN = tok_s[(offi + dir * (sn - 1)) * 32 + n];
            const float* wbn = w_s + tkN * T_ + 4 * h;
            const float4 Wn0 = *(const float4*)(wbn);
            const float4 Wn1 = *(const float4*)(wbn + 8);
            const float4 Wn2 = *(const float4*)(wbn + 16);

            facc16 accA, accB;
            #pragma unroll
            for (int r = 0; r < 16; ++r) { accA[r] = 0.f; accB[r] = 0.f; }
            accA = __builtin_amdgcn_mfma_f32_32x32x16_bf16(
                       __builtin_bit_cast(bf8frag, A1p),
                       __builtin_bit_cast(bf8frag, B1p), accA, 0, 0, 0);
            accB = __builtin_amdgcn_mfma_f32_32x32x16_bf16(
                       __builtin_bit_cast(bf8frag, A2p),
                       __builtin_bit_cast(bf8frag, B2p), accB, 0, 0, 0);

            d[0]  = (accA[0]  + accB[0] ) * Wc0.x;
            d[1]  = (accA[1]  + accB[1] ) * Wc0.y;
            d[2]  = (accA[2]  + accB[2] ) * Wc0.z;
            d[3]  = (accA[3]  + accB[3] ) * Wc0.w;
            d[4]  = (accA[4]  + accB[4] ) * Wc1.x;
            d[5]  = (accA[5]  + accB[5] ) * Wc1.y;
            d[6]  = (accA[6]  + accB[6] ) * Wc1.z;
            d[7]  = (accA[7]  + accB[7] ) * Wc1.w;
            d[8]  = (accA[8]  + accB[8] ) * Wc2.x;
            d[9]  = (accA[9]  + accB[9] ) * Wc2.y;
            d[10] = (accA[10] + accB[10]) * Wc2.z;
            d[11] = (accA[11] + accB[11]) * Wc2.w;

            if ((s & 15) == 0 || s == 63) {
                float mx = d[0];
                #pragma unroll
                for (int r = 1; r < 12; ++r) mx = fmaxf(mx, d[r]);
                mx = fmaxf(mx, __shfl_xor(mx, 32, 64));
                const float inv = 1.0f / mx;
                #pragma unroll
                for (int r = 0; r < 12; ++r) d[r] *= inv;
                logacc += __logf(mx);
            }

            const unsigned P0 = pkbf(d[0], d[1]),  P1 = pkbf(d[2], d[3]);
            const unsigned P2 = pkbf(d[4], d[5]),  P3 = pkbf(d[6], d[7]);
            const unsigned P4 = pkbf(d[8], d[9]),  P5 = pkbf(d[10], d[11]);
            const unsigned XP0 = (unsigned)__shfl_xor((int)P0, 32, 64);
            const unsigned XP1 = (unsigned)__shfl_xor((int)P1, 32, 64);
            const unsigned XP2 = (unsigned)__shfl_xor((int)P2, 32, 64);
            const unsigned XP3 = (unsigned)__shfl_xor((int)P3, 32, 64);
            const unsigned XP4 = (unsigned)__shfl_xor((int)P4, 32, 64);
            const unsigned XP5 = (unsigned)__shfl_xor((int)P5, 32, 64);
            B1p[0] = h ? XP2 : P0;  B1p[1] = h ? XP3 : P1;
            B1p[2] = h ? P2  : XP0; B1p[3] = h ? P3  : XP1;
            B2p[0] = h ? 0u  : P4;  B2p[1] = h ? 0u  : P5;
            B2p[2] = h ? 0u  : XP4; B2p[3] = h ? 0u  : XP5;

            Wc0 = Wn0; Wc1 = Wn1; Wc2 = Wn2;
        }

        if (!isF) {
            #pragma unroll
            for (int r = 0; r < 12; ++r) meet_s[lane * 12 + r] = d[r];
            logb_s[lane] = logacc;
        }
        __syncthreads();
        if (isF) {
            facc16 accA, accB;
            #pragma unroll
            for (int r = 0; r < 16; ++r) { accA[r] = 0.f; accB[r] = 0.f; }
            accA = __builtin_amdgcn_mfma_f32_32x32x16_bf16(
                       __builtin_bit_cast(bf8frag, A1p),
                       __builtin_bit_cast(bf8frag, B1p), accA, 0, 0, 0);
            accB = __builtin_amdgcn_mfma_f32_32x32x16_bf16(
                       __builtin_bit_cast(bf8frag, A2p),
                       __builtin_bit_cast(bf8frag, B2p), accB, 0, 0, 0);
            float dot = 0.f;
            #pragma unroll
            for (int r = 0; r < 12; ++r)
                dot = fmaf(accA[r] + accB[r], meet_s[lane * 12 + r], dot);
            dot += __shfl_xor(dot, 32, 64);
            const float denom = logacc + logb_s[lane] + __logf(dot);
            float val = 0.f;
            if (h == 0)
                val = (denom - gp_s[n]) * (1.0f / (float)B_);
            #pragma unroll
            for (int off = 32; off; off >>= 1)
                val += __shfl_xor(val, off, 64);
            if (lane == 0) atomicAdd(out, val);
        }
    } else {
        // -------- gold (waves 2-3), exact verified math --------
        const int t2 = tid - 128;
        const int n = t2 & 31;
        const int r = t2 >> 5;
        const int b = g * 32 + n;
        const int* __restrict__ lrow = labels + (size_t)b * S_;
        float gp = 0.f;
        for (int i = 0; i < 32; ++i) {
            const int s = r * 32 + i;
            const int tk = tok_s[s * 32 + n];
            const int ls = lrow[s];
            gp += em_table[tk * T_ + ls];
            if (s >= 1) gp -= emax_arr[tk];
            if (s < S_ - 1) gp += trans[ls * T_ + lrow[s + 1]];
            if (s == 0) gp += start_t[ls];
            if (s == S_ - 1) gp += end_t[ls];
        }
        atomicAdd(&gp_s[n], gp);
        __syncthreads();   // pairs with the chain waves' barrier
    }
}

// ---------------------------------------------------------------------------
extern "C" void kernel_launch(void* const* d_in, const int* in_sizes, int n_in,
                              void* d_out, int out_size, void* d_ws, size_t ws_size,
                              hipStream_t stream) {
    const int*   seq     = (const int*)d_in[0];
    const int*   labels  = (const int*)d_in[1];
    // d_in[2] true_lengths: unused by the reference forward
    const float* emb     = (const float*)d_in[3];
    const float* w1      = (const float*)d_in[4];
    const float* b1      = (const float*)d_in[5];
    const float* w2      = (const float*)d_in[6];
    const float* b2      = (const float*)d_in[7];
    const float* start_t = (const float*)d_in[8];
    const float* end_t   = (const float*)d_in[9];
    const float* trans   = (const float*)d_in[10];

    float* ws            = (float*)d_ws;
    unsigned short* w1Tb = (unsigned short*)d_ws;
    float* h_ws          = ws + OFF_H;
    float* em_table      = ws + OFF_EM;
    float* w_table       = ws + OFF_W;
    float* emax_arr      = ws + OFF_MX;
    float* out           = (float*)d_out;

    transpose_kernel<<<64, 256, 0, stream>>>(w1, w1Tb, out);
    h_kernel<<<200, 256, 0, stream>>>(emb, w1Tb, b1, h_ws);
    emis_kernel<<<V_, 256, 0, stream>>>(h_ws, w2, b2, em_table, w_table, emax_arr);
    crf_kernel<<<B_ / 32, 256, 0, stream>>>(seq, labels, start_t, end_t, trans,
                                            em_table, w_table, emax_arr, out);
}

// Round 15
// 109.020 us; speedup vs baseline: 1.7983x; 1.0783x over previous
//
#include <hip/hip_runtime.h>
#include <math.h>

#define PAD_IDX 0
#define BIGV 10000.0f
constexpr int B_ = 1024, S_ = 128, V_ = 200, E_ = 512, H_ = 512, T_ = 24;

// ws layout (float offsets):
constexpr int OFF_H  = 262144;   // h_ws   [200][512]
constexpr int OFF_EM = 364544;   // em_tab [200][24]
constexpr int OFF_W  = 369344;   // w_tab  [200][24]
constexpr int OFF_MX = 374144;   // emax   [200]

typedef __attribute__((ext_vector_type(8)))  short    bf8frag;   // 8 bf16
typedef __attribute__((ext_vector_type(16))) float    facc16;    // MFMA C/D
typedef __attribute__((ext_vector_type(4)))  unsigned u32x4;

__device__ __forceinline__ unsigned pkbf(float lo, float hi) {
    const unsigned a = __float_as_uint(lo), b = __float_as_uint(hi);
    return ((a + 0x8000u) >> 16) | ((b + 0x8000u) & 0xffff0000u);
}

// ---------------------------------------------------------------------------
// Kernel M1 (R15): h = relu(emb @ w1^T + b1) on the MATRIX pipe.
// Replaces transpose_kernel + h_kernel (~6.5us vector-pipe) with one MFMA
// GEMM (~0.7us): grid = 7 v-tiles x 16 t-tiles = 112 blocks. Staging packs
// w1 t-slice and emb v-tile as bf16 pairs DIRECTLY in operand layout
// ([kp][n] u32: elems 2kp,2kp+1), so frag loads are 4 conflict-free
// ds_read_b32. K=512 split 4 ways over waves (8 chained MFMAs each),
// partials combined via padded LDS, bias+relu fused on the coalesced store.
// Fragment layouts HW-verified in R11/R14 (absmax 0.0): A[m=lane&31][k=8h+j],
// B[k=8h+j][n=lane&31], C col=lane&31,row=(reg&3)+8(reg>>2)+4(lane>>5).
// emb row 0 is all zeros -> bf16 exact -> BIG/pad channel unaffected.
// ---------------------------------------------------------------------------
__global__ __launch_bounds__(256) void mlp1_kernel(
    const float* __restrict__ emb, const float* __restrict__ w1,
    const float* __restrict__ b1, float* __restrict__ h_ws,
    float* __restrict__ out)
{
    __shared__ unsigned w1b[256][32];     // B operand: [kp][t-col]
    __shared__ unsigned embb[256][32];    // A operand: [kp][v-row]
    __shared__ float    part[4][64][17];  // K-split partials (+1 pad)
    const int tid = threadIdx.x;
    const int vt = blockIdx.x % 7, tt = blockIdx.x / 7;
    const int v0 = vt * 32, t0 = tt * 32;

    if (blockIdx.x == 0 && tid == 0) out[0] = 0.f;   // crf atomic accumulator

    // ---- stage: w1 slice + emb tile -> bf16 pair-packed operand layout ----
    {
        const int row = tid >> 3;          // 0..31
        const int seg = tid & 7;           // 64 floats each
        {
            const float* __restrict__ src = w1 + (size_t)(t0 + row) * E_ + seg * 64;
            #pragma unroll
            for (int i = 0; i < 16; ++i) {
                const float4 f = *(const float4*)(src + i * 4);
                const int kp = seg * 32 + i * 2;
                w1b[kp][row]     = pkbf(f.x, f.y);
                w1b[kp + 1][row] = pkbf(f.z, f.w);
            }
        }
        const int v = v0 + row;
        if (v < V_) {
            const float* __restrict__ src = emb + (size_t)v * E_ + seg * 64;
            #pragma unroll
            for (int i = 0; i < 16; ++i) {
                const float4 f = *(const float4*)(src + i * 4);
                const int kp = seg * 32 + i * 2;
                embb[kp][row]     = pkbf(f.x, f.y);
                embb[kp + 1][row] = pkbf(f.z, f.w);
            }
        } else {
            #pragma unroll
            for (int i = 0; i < 16; ++i) {
                const int kp = seg * 32 + i * 2;
                embb[kp][row] = 0u; embb[kp + 1][row] = 0u;
            }
        }
    }
    __syncthreads();

    // ---- K-split MFMA: wave w covers k in [w*128, w*128+128) ----
    {
        const int wave = tid >> 6, lane = tid & 63;
        const int mn = lane & 31, h2 = lane >> 5;
        facc16 acc;
        #pragma unroll
        for (int r = 0; r < 16; ++r) acc[r] = 0.f;
        #pragma unroll
        for (int c = 0; c < 8; ++c) {
            const int kp = wave * 64 + c * 8 + 4 * h2;
            u32x4 Af, Bf;
            #pragma unroll
            for (int r = 0; r < 4; ++r) {
                Af[r] = embb[kp + r][mn];
                Bf[r] = w1b[kp + r][mn];
            }
            acc = __builtin_amdgcn_mfma_f32_32x32x16_bf16(
                      __builtin_bit_cast(bf8frag, Af),
                      __builtin_bit_cast(bf8frag, Bf), acc, 0, 0, 0);
        }
        #pragma unroll
        for (int r = 0; r < 16; ++r) part[wave][lane][r] = acc[r];
    }
    __syncthreads();

    // ---- combine partials + bias + relu + coalesced store ----
    {
        const int l = tid & 63, rg = tid >> 6;
        const int col = l & 31, hh = l >> 5;
        const float bb = b1[t0 + col];
        #pragma unroll
        for (int i = 0; i < 4; ++i) {
            const int r = rg * 4 + i;
            const float s = (part[0][l][r] + part[1][l][r])
                          + (part[2][l][r] + part[3][l][r]);
            const int vrow = (r & 3) + 8 * (r >> 2) + 4 * hh;
            const int v = v0 + vrow;
            if (v < V_)
                h_ws[(size_t)v * H_ + t0 + col] = fmaxf(s + bb, 0.f);
        }
    }
}

// ---------------------------------------------------------------------------
// Kernel A2: em_table / w_table / emax (proven R11/R14, unchanged).
// ---------------------------------------------------------------------------
__global__ __launch_bounds__(256) void emis_kernel(
    const float* __restrict__ h_ws, const float* __restrict__ w2,
    const float* __restrict__ b2, float* __restrict__ em_table,
    float* __restrict__ w_table, float* __restrict__ emax_arr)
{
    __shared__ float em_row[32];
    const int v = blockIdx.x;
    const int t = threadIdx.x;
    const int wave = t >> 6, lane = t & 63;
    const float* __restrict__ hrow = h_ws + (size_t)v * H_;
    for (int jj2 = 0; jj2 < 6; ++jj2) {
        const int jo = wave * 6 + jj2;
        float part = 0.f;
        #pragma unroll
        for (int m = 0; m < H_ / 64; ++m) {
            const int k = lane + m * 64;
            part = fmaf(hrow[k], w2[(size_t)jo * H_ + k], part);
        }
        #pragma unroll
        for (int off = 32; off; off >>= 1)
            part += __shfl_xor(part, off, 64);
        if (lane == 0) {
            float val = fmaxf(part + b2[jo], 0.f);
            if (v == 0 && jo == PAD_IDX) val += BIGV;
            em_row[jo] = val;
        }
    }
    __syncthreads();
    if (t < 32) {
        float x = (t < T_) ? em_row[t] : -INFINITY;
        float mx = x;
        #pragma unroll
        for (int off = 16; off; off >>= 1)
            mx = fmaxf(mx, __shfl_xor(mx, off, 32));
        if (t < T_) {
            em_table[v * T_ + t] = x;
            w_table[v * T_ + t]  = __expf(x - mx);
        }
        if (t == 0) emax_arr[v] = mx;
    }
}

// ---------------------------------------------------------------------------
// Kernel B: crf + gold fused (R14, passed absmax 0.0, unchanged).
// ---------------------------------------------------------------------------
__global__ __launch_bounds__(256) void crf_kernel(
    const int* __restrict__ seq, const int* __restrict__ labels,
    const float* __restrict__ start_t, const float* __restrict__ end_t,
    const float* __restrict__ trans, const float* __restrict__ em_table,
    const float* __restrict__ w_table, const float* __restrict__ emax_arr,
    float* __restrict__ out)
{
    __shared__ __align__(16) float w_s[V_ * T_];
    __shared__ int   tok_s[S_ * 32];
    __shared__ float meet_s[64 * 12];
    __shared__ float logb_s[64];
    __shared__ float gp_s[32];
    const int tid = threadIdx.x;
    const int g = blockIdx.x;

    for (int i = tid; i < V_ * T_ / 4; i += 256)
        ((float4*)w_s)[i] = ((const float4*)w_table)[i];
    {
        const int bq = tid & 31, c = tid >> 5;
        const int* __restrict__ src = seq + (size_t)(g * 32 + bq) * S_ + c * 16;
        #pragma unroll
        for (int i = 0; i < 16; ++i)
            tok_s[(c * 16 + i) * 32 + bq] = src[i];
    }
    if (tid < 32) gp_s[tid] = 0.f;
    __syncthreads();

    if (tid < 128) {
        const bool isF = (tid < 64);
        const int lane = tid & 63;
        const int n = lane & 31;
        const int h = lane >> 5;

        u32x4 A1p, A2p;
        {
            float a1e[8], a2e[8];
            #pragma unroll
            for (int j = 0; j < 8; ++j) {
                const int k1 = 8 * h + j;
                const int k2 = 16 + 8 * h + j;
                float v1 = 0.f, v2 = 0.f;
                if (n < T_) {
                    v1 = __expf(isF ? trans[k1 * T_ + n] : trans[n * T_ + k1]);
                    if (k2 < T_)
                        v2 = __expf(isF ? trans[k2 * T_ + n] : trans[n * T_ + k2]);
                }
                a1e[j] = v1; a2e[j] = v2;
            }
            #pragma unroll
            for (int r = 0; r < 4; ++r) {
                A1p[r] = pkbf(a1e[2 * r], a1e[2 * r + 1]);
                A2p[r] = pkbf(a2e[2 * r], a2e[2 * r + 1]);
            }
        }

        float logacc;
        u32x4 B1p, B2p;
        {
            const int tokI = tok_s[(isF ? 0 : (S_ - 1)) * 32 + n];
            float q1[8], q2[8];
            if (isF) {
                float e1[8], e2[8];
                #pragma unroll
                for (int j = 0; j < 8; ++j) { e1[j] = 0.f; e2[j] = 0.f; }
                float mx = -INFINITY;
                #pragma unroll
                for (int j = 0; j < 8; ++j) {
                    const int r1 = 8 * h + j;
                    e1[j] = start_t[r1] + em_table[tokI * T_ + r1];
                    mx = fmaxf(mx, e1[j]);
                }
                if (h == 0) {
                    #pragma unroll
                    for (int j = 0; j < 8; ++j) {
                        const int r2 = 16 + j;
                        e2[j] = start_t[r2] + em_table[tokI * T_ + r2];
                        mx = fmaxf(mx, e2[j]);
                    }
                }
                mx = fmaxf(mx, __shfl_xor(mx, 32, 64));
                #pragma unroll
                for (int j = 0; j < 8; ++j) {
                    q1[j] = __expf(e1[j] - mx);
                    q2[j] = (h == 0) ? __expf(e2[j] - mx) : 0.f;
                }
                logacc = mx;
            } else {
                #pragma unroll
                for (int j = 0; j < 8; ++j) {
                    const int r1 = 8 * h + j;
                    q1[j] = w_s[tokI * T_ + r1] * __expf(end_t[r1]);
                    const int r2 = 16 + j;
                    q2[j] = (h == 0) ? w_s[tokI * T_ + r2] * __expf(end_t[r2]) : 0.f;
                }
                logacc = 0.f;
            }
            #pragma unroll
            for (int r = 0; r < 4; ++r) {
                B1p[r] = pkbf(q1[2 * r], q1[2 * r + 1]);
                B2p[r] = pkbf(q2[2 * r], q2[2 * r + 1]);
            }
        }

        const int dir  = isF ? 1 : -1;
        const int offi = isF ? 1 : (S_ - 2);

        float4 Wc0, Wc1, Wc2;
        {
            const int tk = tok_s[offi * 32 + n];
            const float* wb = w_s + tk * T_ + 4 * h;
            Wc0 = *(const float4*)(wb);
            Wc1 = *(const float4*)(wb + 8);
            Wc2 = *(const float4*)(wb + 16);
        }

        float d[12];
        for (int s = 1; s <= 63; ++s) {
            const int sn = (s < 63) ? (s + 1) : 63;
            const int tkN = tok_s[(offi + dir * (sn - 1)) * 32 + n];
            const float* wbn = w_s + tkN * T_ + 4 * h;
            const float4 Wn0 = *(const float4*)(wbn);
            const float4 Wn1 = *(const float4*)(wbn + 8);
            const float4 Wn2 = *(const float4*)(wbn + 16);

            facc16 accA, accB;
            #pragma unroll
            for (int r = 0; r < 16; ++r) { accA[r] = 0.f; accB[r] = 0.f; }
            accA = __builtin_amdgcn_mfma_f32_32x32x16_bf16(
                       __builtin_bit_cast(bf8frag, A1p),
                       __builtin_bit_cast(bf8frag, B1p), accA, 0, 0, 0);
            accB = __builtin_amdgcn_mfma_f32_32x32x16_bf16(
                       __builtin_bit_cast(bf8frag, A2p),
                       __builtin_bit_cast(bf8frag, B2p), accB, 0, 0, 0);

            d[0]  = (accA[0]  + accB[0] ) * Wc0.x;
            d[1]  = (accA[1]  + accB[1] ) * Wc0.y;
            d[2]  = (accA[2]  + accB[2] ) * Wc0.z;
            d[3]  = (accA[3]  + accB[3] ) * Wc0.w;
            d[4]  = (accA[4]  + accB[4] ) * Wc1.x;
            d[5]  = (accA[5]  + accB[5] ) * Wc1.y;
            d[6]  = (accA[6]  + accB[6] ) * Wc1.z;
            d[7]  = (accA[7]  + accB[7] ) * Wc1.w;
            d[8]  = (accA[8]  + accB[8] ) * Wc2.x;
            d[9]  = (accA[9]  + accB[9] ) * Wc2.y;
            d[10] = (accA[10] + accB[10]) * Wc2.z;
            d[11] = (accA[11] + accB[11]) * Wc2.w;

            if ((s & 15) == 0 || s == 63) {
                float mx = d[0];
                #pragma unroll
                for (int r = 1; r < 12; ++r) mx = fmaxf(mx, d[r]);
                mx = fmaxf(mx, __shfl_xor(mx, 32, 64));
                const float inv = 1.0f / mx;
                #pragma unroll
                for (int r = 0; r < 12; ++r) d[r] *= inv;
                logacc += __logf(mx);
            }

            const unsigned P0 = pkbf(d[0], d[1]),  P1 = pkbf(d[2], d[3]);
            const unsigned P2 = pkbf(d[4], d[5]),  P3 = pkbf(d[6], d[7]);
            const unsigned P4 = pkbf(d[8], d[9]),  P5 = pkbf(d[10], d[11]);
            const unsigned XP0 = (unsigned)__shfl_xor((int)P0, 32, 64);
            const unsigned XP1 = (unsigned)__shfl_xor((int)P1, 32, 64);
            const unsigned XP2 = (unsigned)__shfl_xor((int)P2, 32, 64);
            const unsigned XP3 = (unsigned)__shfl_xor((int)P3, 32, 64);
            const unsigned XP4 = (unsigned)__shfl_xor((int)P4, 32, 64);
            const unsigned XP5 = (unsigned)__shfl_xor((int)P5, 32, 64);
            B1p[0] = h ? XP2 : P0;  B1p[1] = h ? XP3 : P1;
            B1p[2] = h ? P2  : XP0; B1p[3] = h ? P3  : XP1;
            B2p[0] = h ? 0u  : P4;  B2p[1] = h ? 0u  : P5;
            B2p[2] = h ? 0u  : XP4; B2p[3] = h ? 0u  : XP5;

            Wc0 = Wn0; Wc1 = Wn1; Wc2 = Wn2;
        }

        if (!isF) {
            #pragma unroll
            for (int r = 0; r < 12; ++r) meet_s[lane * 12 + r] = d[r];
            logb_s[lane] = logacc;
        }
        __syncthreads();
        if (isF) {
            facc16 accA, accB;
            #pragma unroll
            for (int r = 0; r < 16; ++r) { accA[r] = 0.f; accB[r] = 0.f; }
            accA = __builtin_amdgcn_mfma_f32_32x32x16_bf16(
                       __builtin_bit_cast(bf8frag, A1p),
                       __builtin_bit_cast(bf8frag, B1p), accA, 0, 0, 0);
            accB = __builtin_amdgcn_mfma_f32_32x32x16_bf16(
                       __builtin_bit_cast(bf8frag, A2p),
                       __builtin_bit_cast(bf8frag, B2p), accB, 0, 0, 0);
            float dot = 0.f;
            #pragma unroll
            for (int r = 0; r < 12; ++r)
                dot = fmaf(accA[r] + accB[r], meet_s[lane * 12 + r], dot);
            dot += __shfl_xor(dot, 32, 64);
            const float denom = logacc + logb_s[lane] + __logf(dot);
            float val = 0.f;
            if (h == 0)
                val = (denom - gp_s[n]) * (1.0f / (float)B_);
            #pragma unroll
            for (int off = 32; off; off >>= 1)
                val += __shfl_xor(val, off, 64);
            if (lane == 0) atomicAdd(out, val);
        }
    } else {
        const int t2 = tid - 128;
        const int n = t2 & 31;
        const int r = t2 >> 5;
        const int b = g * 32 + n;
        const int* __restrict__ lrow = labels + (size_t)b * S_;
        float gp = 0.f;
        for (int i = 0; i < 32; ++i) {
            const int s = r * 32 + i;
            const int tk = tok_s[s * 32 + n];
            const int ls = lrow[s];
            gp += em_table[tk * T_ + ls];
            if (s >= 1) gp -= emax_arr[tk];
            if (s < S_ - 1) gp += trans[ls * T_ + lrow[s + 1]];
            if (s == 0) gp += start_t[ls];
            if (s == S_ - 1) gp += end_t[ls];
        }
        atomicAdd(&gp_s[n], gp);
        __syncthreads();
    }
}

// ---------------------------------------------------------------------------
extern "C" void kernel_launch(void* const* d_in, const int* in_sizes, int n_in,
                              void* d_out, int out_size, void* d_ws, size_t ws_size,
                              hipStream_t stream) {
    const int*   seq     = (const int*)d_in[0];
    const int*   labels  = (const int*)d_in[1];
    // d_in[2] true_lengths: unused by the reference forward
    const float* emb     = (const float*)d_in[3];
    const float* w1      = (const float*)d_in[4];
    const float* b1      = (const float*)d_in[5];
    const float* w2      = (const float*)d_in[6];
    const float* b2      = (const float*)d_in[7];
    const float* start_t = (const float*)d_in[8];
    const float* end_t   = (const float*)d_in[9];
    const float* trans   = (const float*)d_in[10];

    float* ws            = (float*)d_ws;
    float* h_ws          = ws + OFF_H;
    float* em_table      = ws + OFF_EM;
    float* w_table       = ws + OFF_W;
    float* emax_arr      = ws + OFF_MX;
    float* out           = (float*)d_out;

    mlp1_kernel<<<112, 256, 0, stream>>>(emb, w1, b1, h_ws, out);
    emis_kernel<<<V_, 256, 0, stream>>>(h_ws, w2, b2, em_table, w_table, emax_arr);
    crf_kernel<<<B_ / 32, 256, 0, stream>>>(seq, labels, start_t, end_t, trans,
                                            em_table, w_table, emax_arr, out);
}